// Round 14
// baseline (716.820 us; speedup 1.0000x reference)
//
#include <hip/hip_runtime.h>
#include <math.h>

namespace {
constexpr int Bc = 64, Lc = 256, DMc = 256;
constexpr int NTc = 20, START_c = 18, STOP_c = 19;
constexpr int ROWSc = Bc * Lc;  // 16384
constexpr float NL2E = -1.4426950408889634f;  // -log2(e)
}

typedef short short8 __attribute__((ext_vector_type(8)));
typedef float f32x4 __attribute__((ext_vector_type(4)));
typedef ushort ushort4v __attribute__((ext_vector_type(4)));
typedef unsigned int uint4v __attribute__((ext_vector_type(4)));

__device__ __forceinline__ ushort f2bf(float x) {
  unsigned u = __float_as_uint(x);
  unsigned r = (u + 0x7FFFu + ((u >> 16) & 1u)) >> 16;
  return (ushort)r;
}
__device__ __forceinline__ float bf2f(ushort h) {
  return __uint_as_float((unsigned)h << 16);
}
__device__ __forceinline__ float vrcp(float x) {
  float r;
  asm("v_rcp_f32 %0, %1" : "=v"(r) : "v"(x));
  return r;
}
__device__ __forceinline__ float vexp2(float x) {
  float r;
  asm("v_exp_f32 %0, %1" : "=v"(r) : "v"(x));
  return r;
}
__device__ __forceinline__ float vlog2(float x) {
  float r;
  asm("v_log_f32 %0, %1" : "=v"(r) : "v"(x));
  return r;
}
__device__ __forceinline__ unsigned cvtpk(float a, float b) {
  unsigned r;
  asm("v_cvt_pk_bf16_f32 %0, %1, %2" : "=v"(r) : "v"(a), "v"(b));
  return r;
}

// ---------------- merged fin + prep (one dispatch) ----------------
__global__ __launch_bounds__(256) void prep_fin_k(
    const int* __restrict__ sent, const int* __restrict__ bush,
    const float* __restrict__ pin, const float* __restrict__ wz,
    const float* __restrict__ twz, const float* __restrict__ emb1,
    const float* __restrict__ emb2, ushort* __restrict__ finb,
    const float* __restrict__ Wq, const float* __restrict__ Wk,
    const float* __restrict__ Wv, const float* __restrict__ Wo,
    const float* __restrict__ Wihf, const float* __restrict__ Wihb,
    const float* __restrict__ Whhf, const float* __restrict__ Whhb,
    const float* __restrict__ Wout,
    const float* __restrict__ bq, const float* __restrict__ bk,
    const float* __restrict__ bv, const float* __restrict__ bo,
    const float* __restrict__ bihf, const float* __restrict__ bihb,
    ushort* __restrict__ wqkv, ushort* __restrict__ wih,
    ushort* __restrict__ whh, float* __restrict__ woutp,
    ushort* __restrict__ woT, float* __restrict__ bqkv,
    float* __restrict__ bcomb, float* __restrict__ zbias) {
  const int tid = threadIdx.x;
  if (blockIdx.x < 16384) {
    const int row = blockIdx.x;
    const int c = tid;
    float v;
    if (c < 100)      v = emb1[(size_t)sent[row] * 100 + c];
    else if (c < 200) v = emb2[(size_t)bush[row] * 100 + (c - 100)];
    else if (c < 220) v = pin[(size_t)row * 20 + (c - 200)];
    else if (c < 238) v = twz[(size_t)row * 18 + (c - 220)];
    else              v = wz[(size_t)row * 18 + (c - 238)];
    finb[(size_t)row * 256 + c] = f2bf(v);
    return;
  }
  const int blk = blockIdx.x - 16384;
  if (blk < 224) {
    const int gid = blk * 256 + tid;
    const int row = gid >> 5;
    if (row < 1792) {
      const int cl = (gid & 31) * 8;
      const float* src;
      ushort* dst;
      if (row < 768) {
        src = (row < 256 ? Wq : (row < 512 ? Wk : Wv)) + (size_t)(row & 255) * 256;
        dst = wqkv + (size_t)row * 256;
      } else {
        const int rr = row - 768;
        src = (rr < 512 ? Wihf + (size_t)rr * 256 : Wihb + (size_t)(rr - 512) * 256);
        dst = wih + (size_t)rr * 256;
      }
      float4 v0 = *(const float4*)(src + cl);
      float4 v1 = *(const float4*)(src + cl + 4);
      short8 o;
      o[0] = (short)f2bf(v0.x); o[1] = (short)f2bf(v0.y); o[2] = (short)f2bf(v0.z); o[3] = (short)f2bf(v0.w);
      o[4] = (short)f2bf(v1.x); o[5] = (short)f2bf(v1.y); o[6] = (short)f2bf(v1.z); o[7] = (short)f2bf(v1.w);
      *(short8*)(dst + cl) = o;
      if (gid < 768) {
        bqkv[gid] = (gid < 256 ? bq[gid] : (gid < 512 ? bk[gid - 256] : bv[gid - 512]));
      }
    }
  } else if (blk < 288) {
    const int gid = (blk - 224) * 256 + tid;
    const int idx = gid * 8;
    const float* src = (idx < 65536) ? (Whhf + idx) : (Whhb + (idx - 65536));
    float4 v0 = *(const float4*)(src);
    float4 v1 = *(const float4*)(src + 4);
    short8 o;
    o[0] = (short)f2bf(v0.x * NL2E); o[1] = (short)f2bf(v0.y * NL2E);
    o[2] = (short)f2bf(v0.z * NL2E); o[3] = (short)f2bf(v0.w * NL2E);
    o[4] = (short)f2bf(v1.x * NL2E); o[5] = (short)f2bf(v1.y * NL2E);
    o[6] = (short)f2bf(v1.z * NL2E); o[7] = (short)f2bf(v1.w * NL2E);
    *(short8*)(whh + idx) = o;
  } else if (blk < 308) {
    const int o = (blk - 288) * 256 + tid;
    const int n = o >> 8, rest = o & 255;
    const int pc = rest >> 2, uu = rest & 3;
    const int dir = pc >> 5, w = (pc >> 2) & 7, kg = pc & 3;
    woutp[o] = Wout[n * 256 + dir * 128 + w * 16 + kg * 4 + uu];
  } else if (blk < 564) {
    const int o = (blk - 308) * 256 + tid;
    const int k = o >> 8, n = o & 255;
    woT[o] = f2bf(Wo[n * 256 + k]);
  } else if (blk < 568) {
    const int j = (blk - 564) * 256 + tid;
    const float* wr = (j < 512) ? (Wihf + (size_t)j * 256) : (Wihb + (size_t)(j - 512) * 256);
    float s = (j < 512) ? bihf[j] : bihb[j - 512];
    for (int k = 0; k < 256; k += 4) {
      float4 w4 = *(const float4*)(wr + k);
      float4 b4 = *(const float4*)(bo + k);
      s += w4.x * b4.x + w4.y * b4.y + w4.z * b4.z + w4.w * b4.w;
    }
    bcomb[j] = s;
  } else {
    zbias[tid] = 0.f;
  }
}

// ---------------- bf16 MFMA GEMM with LDS-staged A (XOR-swizzled): C = A*W^T + bias ----------------
template <int N, bool BF16_OUT>
__global__ __launch_bounds__(256, 2) void mfma_gemm_k(
    const ushort* __restrict__ A, const ushort* __restrict__ W,
    const float* __restrict__ bias, void* __restrict__ Cv) {
  __shared__ __align__(16) ushort As[128 * 256];  // 64KB
  const int tid = threadIdx.x, lane = tid & 63, wid = tid >> 6;
  const int bm = blockIdx.x * 128, bn = blockIdx.y * 128;
  const int wm = (wid >> 1) * 64, wn = (wid & 1) * 64;
  const int r = lane & 15, kg = lane >> 4;
#pragma unroll
  for (int i = 0; i < 16; ++i) {
    const int c = i * 256 + tid;
    const int row = c >> 5, kc = c & 31;
    short8 v = *(const short8*)(A + (size_t)(bm + row) * 256 + kc * 8);
    *(short8*)((char*)As + row * 512 + ((kc * 16) ^ ((row & 7) << 4))) = v;
  }
  const ushort* Wp = W + (size_t)(bn + wn + r) * 256 + kg * 8;
  f32x4 acc[4][4];
#pragma unroll
  for (int i = 0; i < 4; ++i)
#pragma unroll
    for (int j = 0; j < 4; ++j) acc[i][j] = (f32x4){0.f, 0.f, 0.f, 0.f};
  __syncthreads();
#pragma unroll
  for (int k0 = 0; k0 < 256; k0 += 32) {
    short8 a[4], b[4];
#pragma unroll
    for (int fi = 0; fi < 4; ++fi) {
      const int row = wm + fi * 16 + r;
      a[fi] = *(const short8*)((const char*)As + row * 512 +
                               ((k0 * 2 + kg * 16) ^ ((row & 7) << 4)));
    }
#pragma unroll
    for (int fj = 0; fj < 4; ++fj) b[fj] = *(const short8*)(Wp + fj * 16 * 256 + k0);
#pragma unroll
    for (int fi = 0; fi < 4; ++fi)
#pragma unroll
      for (int fj = 0; fj < 4; ++fj)
        acc[fi][fj] = __builtin_amdgcn_mfma_f32_16x16x32_bf16(a[fi], b[fj], acc[fi][fj], 0, 0, 0);
  }
#pragma unroll
  for (int fi = 0; fi < 4; ++fi)
#pragma unroll
    for (int fj = 0; fj < 4; ++fj) {
      const int n = bn + wn + fj * 16 + r;
      const float bn_ = bias[n];
#pragma unroll
      for (int rr = 0; rr < 4; ++rr) {
        const int m = bm + wm + fi * 16 + kg * 4 + rr;
        const float v = acc[fi][fj][rr] + bn_;
        if (BF16_OUT) ((ushort*)Cv)[(size_t)m * N + n] = f2bf(v);
        else          ((float*)Cv)[(size_t)m * N + n] = v;
      }
    }
}

// ---------------- MFMA attention (unchanged) ----------------
__global__ __launch_bounds__(256) void attn_mfma_k(
    const ushort* __restrict__ qkv, ushort* __restrict__ xout) {
  extern __shared__ ushort smem[];
  ushort* Klds = smem;
  ushort* Vlds = smem + 16384;
  const int bh = blockIdx.x;
  const int b = bh >> 2, h = bh & 3;
  const int tid = threadIdx.x;
  const int lane = tid & 63, w = tid >> 6;
  const int r = lane & 15, kg = lane >> 4;
  const ushort* qb = qkv + (size_t)(b * Lc) * 768 + h * 64;
  const ushort* kb = qb + 256;
  const ushort* vb = qb + 512;
#pragma unroll
  for (int i = 0; i < 8; ++i) {
    const int c = i * 256 + tid;
    const int key = c >> 3, kc = c & 7;
    short8 v = *(const short8*)(kb + (size_t)key * 768 + kc * 8);
    *(short8*)((char*)Klds + key * 128 + ((kc * 16) ^ ((key & 7) << 4))) = v;
  }
#pragma unroll
  for (int i = 0; i < 8; ++i) {
    const int c = i * 256 + tid;
    const int key = c >> 3, dc = c & 7;
    short8 v = *(const short8*)(vb + (size_t)key * 768 + dc * 8);
#pragma unroll
    for (int j = 0; j < 8; ++j) {
      const int d = dc * 8 + j;
      *(ushort*)((char*)Vlds + d * 512 + ((key * 2) ^ ((d & 7) << 4))) = (ushort)v[j];
    }
  }
  __syncthreads();

#pragma unroll 1
  for (int it = 0; it < 4; ++it) {
    const int qbase = it * 64 + w * 16;
    short8 bq0 = *(const short8*)(qb + (size_t)(qbase + r) * 768 + kg * 8);
    short8 bq1 = *(const short8*)(qb + (size_t)(qbase + r) * 768 + 32 + kg * 8);
    f32x4 accs[16];
#pragma unroll
    for (int fi = 0; fi < 16; ++fi) accs[fi] = (f32x4){0.f, 0.f, 0.f, 0.f};
#pragma unroll
    for (int fi = 0; fi < 16; ++fi) {
      const int key = fi * 16 + r;
      short8 ak0 = *(const short8*)((const char*)Klds + key * 128 + ((kg * 16) ^ ((key & 7) << 4)));
      short8 ak1 = *(const short8*)((const char*)Klds + key * 128 + ((64 + kg * 16) ^ ((key & 7) << 4)));
      accs[fi] = __builtin_amdgcn_mfma_f32_16x16x32_bf16(ak0, bq0, accs[fi], 0, 0, 0);
      accs[fi] = __builtin_amdgcn_mfma_f32_16x16x32_bf16(ak1, bq1, accs[fi], 0, 0, 0);
    }
    float m = -1e30f;
#pragma unroll
    for (int fi = 0; fi < 16; ++fi)
#pragma unroll
      for (int rr = 0; rr < 4; ++rr) m = fmaxf(m, accs[fi][rr]);
    m = fmaxf(m, __shfl_xor(m, 16));
    m = fmaxf(m, __shfl_xor(m, 32));
    float den = 0.f;
#pragma unroll
    for (int fi = 0; fi < 16; ++fi)
#pragma unroll
      for (int rr = 0; rr < 4; ++rr) {
        const float e = __expf((accs[fi][rr] - m) * 0.125f);
        accs[fi][rr] = e;
        den += e;
      }
    den += __shfl_xor(den, 16);
    den += __shfl_xor(den, 32);
    const float rp = vrcp(den);
    unsigned u[16][2];
#pragma unroll
    for (int fi = 0; fi < 16; ++fi) {
      u[fi][0] = cvtpk(accs[fi][0] * rp, accs[fi][1] * rp);
      u[fi][1] = cvtpk(accs[fi][2] * rp, accs[fi][3] * rp);
    }
    short8 bpv[8];
#pragma unroll
    for (int ks2 = 0; ks2 < 8; ++ks2) {
      uint4v vals;
#pragma unroll
      for (int m2 = 0; m2 < 4; ++m2) {
        const int src = r + (((kg & 1) * 2 + (m2 >> 1)) << 4);
        const unsigned lo = __shfl(u[2 * ks2][m2 & 1], src);
        const unsigned hi = __shfl(u[2 * ks2 + 1][m2 & 1], src);
        vals[m2] = (kg >= 2) ? hi : lo;
      }
      union { uint4v u4; short8 s8; } cv;
      cv.u4 = vals;
      bpv[ks2] = cv.s8;
    }
    f32x4 acco[4];
#pragma unroll
    for (int fj = 0; fj < 4; ++fj) acco[fj] = (f32x4){0.f, 0.f, 0.f, 0.f};
#pragma unroll
    for (int fj = 0; fj < 4; ++fj) {
      const int d = fj * 16 + r;
#pragma unroll
      for (int ks2 = 0; ks2 < 8; ++ks2) {
        short8 bv = *(const short8*)((const char*)Vlds + d * 512 +
                                     ((ks2 * 64 + kg * 16) ^ ((d & 7) << 4)));
        acco[fj] = __builtin_amdgcn_mfma_f32_16x16x32_bf16(bpv[ks2], bv, acco[fj], 0, 0, 0);
      }
    }
#pragma unroll
    for (int fj = 0; fj < 4; ++fj)
#pragma unroll
      for (int rr = 0; rr < 4; ++rr) {
        const int q = qbase + kg * 4 + rr;
        xout[((size_t)(b * Lc + q)) * 256 + h * 64 + fj * 16 + r] = f2bf(acco[fj][rr]);
      }
  }
}

// ---------------- transpose gx -> gxt [s][dir][grow][b][r], fold bhh, scale by -log2e ----------------
__global__ __launch_bounds__(256) void transpose_gx_k(
    const ushort* __restrict__ gx, const float* __restrict__ bhhf,
    const float* __restrict__ bhhb, ushort* __restrict__ gxt) {
  const int s = blockIdx.x, dir = blockIdx.y;
  const int t = threadIdx.x;
  const int b = t & 63;
  const int c = t >> 6;
  const float* bhh = dir ? bhhb : bhhf;
  const size_t obase = (size_t)(s * 2 + dir) * 32768;
#pragma unroll 4
  for (int i = 0; i < 16; ++i) {
    const int g8 = i * 4 + c;
    short8 v = *(const short8*)(gx + ((size_t)b * 256 + s) * 1024 + dir * 512 + g8 * 8);
    float f[8];
#pragma unroll
    for (int j = 0; j < 8; ++j) f[j] = (bf2f((ushort)v[j]) + bhh[g8 * 8 + j]) * NL2E;
    uint2 lo = make_uint2(cvtpk(f[0], f[1]), cvtpk(f[2], f[3]));
    uint2 hi = make_uint2(cvtpk(f[4], f[5]), cvtpk(f[6], f[7]));
    *(uint2*)(gxt + obase + (size_t)(g8 * 2) * 256 + b * 4) = lo;
    *(uint2*)(gxt + obase + (size_t)(g8 * 2 + 1) * 256 + b * 4) = hi;
  }
}

// ---------------- MFMA BiLSTM: both directions in ONE block (16 waves) for latency co-schedule ------
// waves 0-7: dir 0, waves 8-15: dir 1. Per-dir private hlds double-buffer; shared block barrier.
__global__ __launch_bounds__(1024, 1) void lstm_mfma_k(
    const ushort* __restrict__ gxt, const ushort* __restrict__ whh,
    const float* __restrict__ h0, const float* __restrict__ c0,
    ushort* __restrict__ louts) {
  const int bs = blockIdx.x * 16;
  const int tid = threadIdx.x;
  const int dir = tid >> 9;
  const int w = (tid >> 6) & 7, lane = tid & 63;
  const int col = lane & 15;
  const int kg = lane >> 4;
  short8 afrag[4][4];
#pragma unroll
  for (int g = 0; g < 4; ++g)
#pragma unroll
    for (int ks = 0; ks < 4; ++ks)
      afrag[g][ks] = *(const short8*)(whh + (size_t)dir * 65536 +
                                      (size_t)(g * 128 + w * 16 + col) * 128 + ks * 32 + kg * 8);
  float4 c4 = *(const float4*)(c0 + (size_t)(dir * Bc + bs + col) * 128 + w * 16 + kg * 4);
  __shared__ __align__(16) ushort hlds[2][2][2048];  // [dir][buf][...]
  {
    float4 h4 = *(const float4*)(h0 + (size_t)(dir * Bc + bs + col) * 128 + w * 16 + kg * 4);
    const int wb = (col * 256 + w * 32 + kg * 8) ^ ((col & 7) << 4);
    *(uint2*)((char*)hlds[dir][0] + wb) = make_uint2(cvtpk(h4.x, h4.y), cvtpk(h4.z, h4.w));
  }
  const ushort* gtb = gxt + (size_t)dir * 32768 + (size_t)(w * 4 + kg) * 256 + (size_t)(bs + col) * 4;
  const int step0 = dir ? (Lc - 1) : 0;
  const int dstep = dir ? -1 : 1;
  const ptrdiff_t gstride = (ptrdiff_t)dstep * 65536;
  const ptrdiff_t lstride = (ptrdiff_t)dstep * 16384;
  ushort4v gA[4], gB[4];
#pragma unroll
  for (int g = 0; g < 4; ++g) gA[g] = *(const ushort4v*)(gtb + (size_t)step0 * 65536 + g * 8192);
#pragma unroll
  for (int g = 0; g < 4; ++g) gB[g] = *(const ushort4v*)(gtb + (size_t)(step0 + dstep) * 65536 + g * 8192);
  const ushort* gld = gtb + (size_t)step0 * 65536 + 2 * gstride;
  ushort* lst = louts + (size_t)step0 * 16384 + dir * 8192 + w * 1024 + kg * 256 +
                (size_t)(bs + col) * 4;
  __syncthreads();
  int p = 0;

  auto body = [&](ushort4v (&gcur)[4], bool pfok) {
    short8 bfrag[4];
#pragma unroll
    for (int ks = 0; ks < 4; ++ks) {
      const int rb = (col * 256 + ks * 64 + kg * 16) ^ ((col & 7) << 4);
      bfrag[ks] = *(const short8*)((const char*)hlds[dir][p] + rb);
    }
    f32x4 acc[4];
#pragma unroll
    for (int g = 0; g < 4; ++g)
      acc[g] = (f32x4){bf2f(gcur[g][0]), bf2f(gcur[g][1]), bf2f(gcur[g][2]), bf2f(gcur[g][3])};
    if (pfok) {
#pragma unroll
      for (int g = 0; g < 4; ++g) gcur[g] = *(const ushort4v*)(gld + g * 8192);
      gld += gstride;
    }
#pragma unroll
    for (int ks = 0; ks < 4; ++ks)
#pragma unroll
      for (int g = 0; g < 4; ++g)
        acc[g] = __builtin_amdgcn_mfma_f32_16x16x32_bf16(afrag[g][ks], bfrag[ks], acc[g], 0, 0, 0);
    f32x4 hr;
#pragma unroll
    for (int r = 0; r < 4; ++r) {
      const float ii = vrcp(1.f + vexp2(acc[0][r]));
      const float ff = vrcp(1.f + vexp2(acc[1][r]));
      const float gg = fmaf(-2.f, vrcp(1.f + vexp2(acc[2][r] * -2.f)), 1.f);
      const float oo = vrcp(1.f + vexp2(acc[3][r]));
      const float cn = ff * c4[r] + ii * gg;
      c4[r] = cn;
      const float tc = fmaf(-2.f, vrcp(1.f + vexp2(cn * 2.8853900817779268f)), 1.f);
      hr[r] = oo * tc;
    }
    const uint2 hp2 = make_uint2(cvtpk(hr[0], hr[1]), cvtpk(hr[2], hr[3]));
    const int wb = (col * 256 + w * 32 + kg * 8) ^ ((col & 7) << 4);
    *(uint2*)((char*)hlds[dir][p ^ 1] + wb) = hp2;
    *(uint2*)lst = hp2;
    lst += lstride;
    asm volatile("s_waitcnt lgkmcnt(0)" ::: "memory");
    __builtin_amdgcn_s_barrier();
    asm volatile("" ::: "memory");
    p ^= 1;
  };

  for (int s = 0; s < Lc; s += 2) {
    body(gA, s + 2 < Lc);
    body(gB, s + 3 < Lc);
  }
}

// ---------------- logits (unchanged) ----------------
__global__ __launch_bounds__(256) void logits_k(
    const ushort* __restrict__ louts, const float* __restrict__ woutp,
    const float* __restrict__ bout, float* __restrict__ lg) {
  const int s = blockIdx.x;
  const int t = threadIdx.x;
  __shared__ float wls[20 * 256];
  __shared__ float bls[20];
  for (int i = t; i < 20 * 256; i += 256) wls[i] = woutp[i];
  if (t < 20) bls[t] = bout[t];
  __syncthreads();
  const int b = t & 63, tg = t >> 6;
  const ushort* src = louts + (size_t)s * 16384 + b * 4;
  float acc[5] = {0.f, 0.f, 0.f, 0.f, 0.f};
  for (int pc = 0; pc < 64; ++pc) {
    ushort4v x4 = *(const ushort4v*)(src + pc * 256);
    const float x0 = bf2f(x4[0]), x1 = bf2f(x4[1]), x2 = bf2f(x4[2]), x3 = bf2f(x4[3]);
#pragma unroll
    for (int n = 0; n < 5; ++n) {
      const float* w4 = wls + (tg * 5 + n) * 256 + pc * 4;
      acc[n] += x0 * w4[0] + x1 * w4[1] + x2 * w4[2] + x3 * w4[3];
    }
  }
#pragma unroll
  for (int n = 0; n < 5; ++n)
    lg[((size_t)b * Lc + s) * NTc + tg * 5 + n] = acc[n] + bls[tg * 5 + n];
}

// ---------------- CRF: single-wave shfl scan in log2 space (unchanged) ----------------
__global__ __launch_bounds__(64) void crf_fwd_k(
    const float* __restrict__ lg, const int* __restrict__ tags,
    const int* __restrict__ lens, const float* __restrict__ tr,
    float* __restrict__ part) {
  const int b = blockIdx.x, j = threadIdx.x;
  const float L2E = 1.4426950408889634f;
  __shared__ float tl[NTc * NTc];
  for (int i = j; i < NTc * NTc; i += 64) tl[i] = tr[i];
  __syncthreads();
  const int len = lens[b];
  float gv = 0.f;
  for (int t = j; t < len; t += 64) {
    const int tag = tags[b * Lc + t];
    const int pv = (t == 0) ? START_c : tags[b * Lc + t - 1];
    gv += lg[((size_t)b * Lc + t) * NTc + tag] + tl[pv * NTc + tag];
  }
#pragma unroll
  for (int off = 32; off > 0; off >>= 1) gv += __shfl_xor(gv, off);
  const int jj = (j < NTc) ? j : 0;
  float trc2[NTc];
#pragma unroll
  for (int i = 0; i < NTc; ++i) trc2[i] = tl[i * NTc + jj] * L2E;
  float prev2 = 0.f;
  float lgn = lg[(size_t)b * Lc * NTc + jj];
  for (int t = 0; t < len; ++t) {
    const float lg2 = lgn * L2E;
    if (t + 1 < len) lgn = lg[((size_t)b * Lc + t + 1) * NTc + jj];
    float v[NTc];
#pragma unroll
    for (int i = 0; i < NTc; ++i) v[i] = __shfl(prev2, i) + trc2[i];
    float a0 = fmaxf(v[0], v[1]), a1 = fmaxf(v[2], v[3]), a2 = fmaxf(v[4], v[5]);
    float a3 = fmaxf(v[6], v[7]), a4 = fmaxf(v[8], v[9]), a5 = fmaxf(v[10], v[11]);
    float a6 = fmaxf(v[12], v[13]), a7 = fmaxf(v[14], v[15]), a8 = fmaxf(v[16], v[17]);
    float a9 = fmaxf(v[18], v[19]);
    float b0 = fmaxf(fmaxf(a0, a1), a2), b1 = fmaxf(fmaxf(a3, a4), a5);
    float b2 = fmaxf(fmaxf(a6, a7), a8);
    const float m = fmaxf(fmaxf(b0, b1), fmaxf(b2, a9));
    float s0 = 0.f, s1 = 0.f, s2 = 0.f, s3 = 0.f;
#pragma unroll
    for (int i = 0; i < NTc; i += 4) {
      s0 += vexp2(v[i] - m);
      s1 += vexp2(v[i + 1] - m);
      s2 += vexp2(v[i + 2] - m);
      s3 += vexp2(v[i + 3] - m);
    }
    prev2 = m + vlog2((s0 + s1) + (s2 + s3)) + lg2;
  }
  float fv[NTc];
#pragma unroll
  for (int i = 0; i < NTc; ++i) fv[i] = __shfl(prev2, i) + tl[i * NTc + STOP_c] * L2E;
  float a0 = fmaxf(fv[0], fv[1]), a1 = fmaxf(fv[2], fv[3]), a2 = fmaxf(fv[4], fv[5]);
  float a3 = fmaxf(fv[6], fv[7]), a4 = fmaxf(fv[8], fv[9]), a5 = fmaxf(fv[10], fv[11]);
  float a6 = fmaxf(fv[12], fv[13]), a7 = fmaxf(fv[14], fv[15]), a8 = fmaxf(fv[16], fv[17]);
  float a9 = fmaxf(fv[18], fv[19]);
  float b0 = fmaxf(fmaxf(a0, a1), a2), b1 = fmaxf(fmaxf(a3, a4), a5);
  float b2 = fmaxf(fmaxf(a6, a7), a8);
  const float m = fmaxf(fmaxf(b0, b1), fmaxf(b2, a9));
  float ssum = 0.f;
#pragma unroll
  for (int i = 0; i < NTc; ++i) ssum += vexp2(fv[i] - m);
  if (j == 0) {
    const int lt = tags[b * Lc + len - 1];
    const float realv = gv + tl[lt * NTc + STOP_c];
    const float total = (m + vlog2(ssum)) * 0.6931471805599453f;
    part[b] = total - realv;
  }
}

__global__ __launch_bounds__(64) void final_sum_k(const float* __restrict__ part, float* __restrict__ out) {
  float v = part[threadIdx.x];
#pragma unroll
  for (int off = 32; off > 0; off >>= 1) v += __shfl_down(v, off);
  if (threadIdx.x == 0) out[0] = v;
}

extern "C" void kernel_launch(void* const* d_in, const int* in_sizes, int n_in,
                              void* d_out, int out_size, void* d_ws, size_t ws_size,
                              hipStream_t stream) {
  const int* sent = (const int*)d_in[0];
  const int* bush = (const int*)d_in[1];
  const float* pin = (const float*)d_in[2];
  const float* wz = (const float*)d_in[3];
  const float* twz = (const float*)d_in[4];
  const int* tags = (const int*)d_in[5];
  const int* lens = (const int*)d_in[6];
  const float* emb1 = (const float*)d_in[7];
  const float* emb2 = (const float*)d_in[8];
  const float* Wq = (const float*)d_in[9];  const float* bq = (const float*)d_in[10];
  const float* Wk = (const float*)d_in[11]; const float* bk = (const float*)d_in[12];
  const float* Wv = (const float*)d_in[13]; const float* bv = (const float*)d_in[14];
  const float* Wo = (const float*)d_in[15]; const float* bo = (const float*)d_in[16];
  const float* Wihf = (const float*)d_in[17]; const float* Whhf = (const float*)d_in[18];
  const float* bihf = (const float*)d_in[19]; const float* bhhf = (const float*)d_in[20];
  const float* Wihb = (const float*)d_in[21]; const float* Whhb = (const float*)d_in[22];
  const float* bihb = (const float*)d_in[23]; const float* bhhb = (const float*)d_in[24];
  const float* Wout = (const float*)d_in[25]; const float* bout = (const float*)d_in[26];
  const float* trans = (const float*)d_in[27];
  const float* h0 = (const float*)d_in[28]; const float* c0 = (const float*)d_in[29];
  float* out = (float*)d_out;
  float* w = (float*)d_ws;
  ushort* finb  = (ushort*)w;
  ushort* axb   = (ushort*)w;
  ushort* qkvb  = (ushort*)(w + 2097152);
  ushort* gxb   = (ushort*)(w + 8388608);
  ushort* gxt   = (ushort*)w;
  ushort* louts = (ushort*)(w + 8388608);
  float*  lgts  = w + 10485760;
  size_t off = 16777216;
  ushort* wqkvb  = (ushort*)(w + off); off += 768 * 256 / 2;
  ushort* wihbf  = (ushort*)(w + off); off += 1024 * 256 / 2;
  ushort* woTb   = (ushort*)(w + off); off += 256 * 256 / 2;
  ushort* wcombb = (ushort*)(w + off); off += 1024 * 256 / 2;
  ushort* whhp   = (ushort*)(w + off); off += 2 * 512 * 128 / 2;
  float* woutp = w + off; off += 20 * 256;
  float* bqkv  = w + off; off += 768;
  float* bcomb = w + off; off += 1024;
  float* zbias = w + off; off += 256;
  float* partv = w + off;

  prep_fin_k<<<16384 + 569, 256, 0, stream>>>(
      sent, bush, pin, wz, twz, emb1, emb2, finb,
      Wq, Wk, Wv, Wo, Wihf, Wihb, Whhf, Whhb, Wout,
      bq, bk, bv, bo, bihf, bihb,
      wqkvb, wihbf, whhp, woutp, woTb, bqkv, bcomb, zbias);
  // Wcomb[j][k] = sum_n Wih[j][n] * Wo[n][k]
  mfma_gemm_k<256, true><<<dim3(8, 2), 256, 0, stream>>>(wihbf, woTb, zbias, wcombb);
  mfma_gemm_k<768, true><<<dim3(128, 6), 256, 0, stream>>>(finb, wqkvb, bqkv, qkvb);
  attn_mfma_k<<<Bc * 4, 256, 65536, stream>>>(qkvb, axb);
  // gx = attn_out @ Wcomb^T + bcomb   (O-proj fused in)
  mfma_gemm_k<1024, true><<<dim3(128, 8), 256, 0, stream>>>(axb, wcombb, bcomb, gxb);
  transpose_gx_k<<<dim3(256, 2), 256, 0, stream>>>(gxb, bhhf, bhhb, gxt);
  lstm_mfma_k<<<4, 1024, 0, stream>>>(gxt, whhp, h0, c0, louts);
  logits_k<<<Lc, 256, 0, stream>>>(louts, woutp, bout, lgts);
  crf_fwd_k<<<Bc, 64, 0, stream>>>(lgts, tags, lens, trans, partv);
  final_sum_k<<<1, 64, 0, stream>>>(partv, out);
}

// Round 15
// 463.126 us; speedup vs baseline: 1.5478x; 1.5478x over previous
//
#include <hip/hip_runtime.h>
#include <math.h>

namespace {
constexpr int Bc = 64, Lc = 256, DMc = 256;
constexpr int NTc = 20, START_c = 18, STOP_c = 19;
constexpr int ROWSc = Bc * Lc;  // 16384
constexpr float NL2E = -1.4426950408889634f;  // -log2(e)
}

typedef short short8 __attribute__((ext_vector_type(8)));
typedef float f32x4 __attribute__((ext_vector_type(4)));
typedef ushort ushort4v __attribute__((ext_vector_type(4)));
typedef unsigned int uint4v __attribute__((ext_vector_type(4)));

__device__ __forceinline__ ushort f2bf(float x) {
  unsigned u = __float_as_uint(x);
  unsigned r = (u + 0x7FFFu + ((u >> 16) & 1u)) >> 16;
  return (ushort)r;
}
__device__ __forceinline__ float bf2f(ushort h) {
  return __uint_as_float((unsigned)h << 16);
}
__device__ __forceinline__ float vrcp(float x) {
  float r;
  asm("v_rcp_f32 %0, %1" : "=v"(r) : "v"(x));
  return r;
}
__device__ __forceinline__ float vexp2(float x) {
  float r;
  asm("v_exp_f32 %0, %1" : "=v"(r) : "v"(x));
  return r;
}
__device__ __forceinline__ float vlog2(float x) {
  float r;
  asm("v_log_f32 %0, %1" : "=v"(r) : "v"(x));
  return r;
}
__device__ __forceinline__ unsigned cvtpk(float a, float b) {
  unsigned r;
  asm("v_cvt_pk_bf16_f32 %0, %1, %2" : "=v"(r) : "v"(a), "v"(b));
  return r;
}

// ---------------- merged fin + prep (one dispatch) ----------------
__global__ __launch_bounds__(256) void prep_fin_k(
    const int* __restrict__ sent, const int* __restrict__ bush,
    const float* __restrict__ pin, const float* __restrict__ wz,
    const float* __restrict__ twz, const float* __restrict__ emb1,
    const float* __restrict__ emb2, ushort* __restrict__ finb,
    const float* __restrict__ Wq, const float* __restrict__ Wk,
    const float* __restrict__ Wv, const float* __restrict__ Wo,
    const float* __restrict__ Wihf, const float* __restrict__ Wihb,
    const float* __restrict__ Whhf, const float* __restrict__ Whhb,
    const float* __restrict__ Wout,
    const float* __restrict__ bq, const float* __restrict__ bk,
    const float* __restrict__ bv, const float* __restrict__ bo,
    const float* __restrict__ bihf, const float* __restrict__ bihb,
    ushort* __restrict__ wqkv, ushort* __restrict__ wih,
    ushort* __restrict__ whh, float* __restrict__ woutp,
    ushort* __restrict__ woT, float* __restrict__ bqkv,
    float* __restrict__ bcomb, float* __restrict__ zbias) {
  const int tid = threadIdx.x;
  if (blockIdx.x < 16384) {
    const int row = blockIdx.x;
    const int c = tid;
    float v;
    if (c < 100)      v = emb1[(size_t)sent[row] * 100 + c];
    else if (c < 200) v = emb2[(size_t)bush[row] * 100 + (c - 100)];
    else if (c < 220) v = pin[(size_t)row * 20 + (c - 200)];
    else if (c < 238) v = twz[(size_t)row * 18 + (c - 220)];
    else              v = wz[(size_t)row * 18 + (c - 238)];
    finb[(size_t)row * 256 + c] = f2bf(v);
    return;
  }
  const int blk = blockIdx.x - 16384;
  if (blk < 224) {
    const int gid = blk * 256 + tid;
    const int row = gid >> 5;
    if (row < 1792) {
      const int cl = (gid & 31) * 8;
      const float* src;
      ushort* dst;
      if (row < 768) {
        src = (row < 256 ? Wq : (row < 512 ? Wk : Wv)) + (size_t)(row & 255) * 256;
        dst = wqkv + (size_t)row * 256;
      } else {
        const int rr = row - 768;
        src = (rr < 512 ? Wihf + (size_t)rr * 256 : Wihb + (size_t)(rr - 512) * 256);
        dst = wih + (size_t)rr * 256;
      }
      float4 v0 = *(const float4*)(src + cl);
      float4 v1 = *(const float4*)(src + cl + 4);
      short8 o;
      o[0] = (short)f2bf(v0.x); o[1] = (short)f2bf(v0.y); o[2] = (short)f2bf(v0.z); o[3] = (short)f2bf(v0.w);
      o[4] = (short)f2bf(v1.x); o[5] = (short)f2bf(v1.y); o[6] = (short)f2bf(v1.z); o[7] = (short)f2bf(v1.w);
      *(short8*)(dst + cl) = o;
      if (gid < 768) {
        bqkv[gid] = (gid < 256 ? bq[gid] : (gid < 512 ? bk[gid - 256] : bv[gid - 512]));
      }
    }
  } else if (blk < 288) {
    const int gid = (blk - 224) * 256 + tid;
    const int idx = gid * 8;
    const float* src = (idx < 65536) ? (Whhf + idx) : (Whhb + (idx - 65536));
    float4 v0 = *(const float4*)(src);
    float4 v1 = *(const float4*)(src + 4);
    short8 o;
    o[0] = (short)f2bf(v0.x * NL2E); o[1] = (short)f2bf(v0.y * NL2E);
    o[2] = (short)f2bf(v0.z * NL2E); o[3] = (short)f2bf(v0.w * NL2E);
    o[4] = (short)f2bf(v1.x * NL2E); o[5] = (short)f2bf(v1.y * NL2E);
    o[6] = (short)f2bf(v1.z * NL2E); o[7] = (short)f2bf(v1.w * NL2E);
    *(short8*)(whh + idx) = o;
  } else if (blk < 308) {
    const int o = (blk - 288) * 256 + tid;
    const int n = o >> 8, rest = o & 255;
    const int pc = rest >> 2, uu = rest & 3;
    const int dir = pc >> 5, w = (pc >> 2) & 7, kg = pc & 3;
    woutp[o] = Wout[n * 256 + dir * 128 + w * 16 + kg * 4 + uu];
  } else if (blk < 564) {
    const int o = (blk - 308) * 256 + tid;
    const int k = o >> 8, n = o & 255;
    woT[o] = f2bf(Wo[n * 256 + k]);
  } else if (blk < 568) {
    const int j = (blk - 564) * 256 + tid;
    const float* wr = (j < 512) ? (Wihf + (size_t)j * 256) : (Wihb + (size_t)(j - 512) * 256);
    float s = (j < 512) ? bihf[j] : bihb[j - 512];
    for (int k = 0; k < 256; k += 4) {
      float4 w4 = *(const float4*)(wr + k);
      float4 b4 = *(const float4*)(bo + k);
      s += w4.x * b4.x + w4.y * b4.y + w4.z * b4.z + w4.w * b4.w;
    }
    bcomb[j] = s;
  } else {
    zbias[tid] = 0.f;
  }
}

// ---------------- bf16 MFMA GEMM with LDS-staged A (XOR-swizzled): C = A*W^T + bias ----------------
template <int N, bool BF16_OUT>
__global__ __launch_bounds__(256, 2) void mfma_gemm_k(
    const ushort* __restrict__ A, const ushort* __restrict__ W,
    const float* __restrict__ bias, void* __restrict__ Cv) {
  __shared__ __align__(16) ushort As[128 * 256];  // 64KB
  const int tid = threadIdx.x, lane = tid & 63, wid = tid >> 6;
  const int bm = blockIdx.x * 128, bn = blockIdx.y * 128;
  const int wm = (wid >> 1) * 64, wn = (wid & 1) * 64;
  const int r = lane & 15, kg = lane >> 4;
#pragma unroll
  for (int i = 0; i < 16; ++i) {
    const int c = i * 256 + tid;
    const int row = c >> 5, kc = c & 31;
    short8 v = *(const short8*)(A + (size_t)(bm + row) * 256 + kc * 8);
    *(short8*)((char*)As + row * 512 + ((kc * 16) ^ ((row & 7) << 4))) = v;
  }
  const ushort* Wp = W + (size_t)(bn + wn + r) * 256 + kg * 8;
  f32x4 acc[4][4];
#pragma unroll
  for (int i = 0; i < 4; ++i)
#pragma unroll
    for (int j = 0; j < 4; ++j) acc[i][j] = (f32x4){0.f, 0.f, 0.f, 0.f};
  __syncthreads();
#pragma unroll
  for (int k0 = 0; k0 < 256; k0 += 32) {
    short8 a[4], b[4];
#pragma unroll
    for (int fi = 0; fi < 4; ++fi) {
      const int row = wm + fi * 16 + r;
      a[fi] = *(const short8*)((const char*)As + row * 512 +
                               ((k0 * 2 + kg * 16) ^ ((row & 7) << 4)));
    }
#pragma unroll
    for (int fj = 0; fj < 4; ++fj) b[fj] = *(const short8*)(Wp + fj * 16 * 256 + k0);
#pragma unroll
    for (int fi = 0; fi < 4; ++fi)
#pragma unroll
      for (int fj = 0; fj < 4; ++fj)
        acc[fi][fj] = __builtin_amdgcn_mfma_f32_16x16x32_bf16(a[fi], b[fj], acc[fi][fj], 0, 0, 0);
  }
#pragma unroll
  for (int fi = 0; fi < 4; ++fi)
#pragma unroll
    for (int fj = 0; fj < 4; ++fj) {
      const int n = bn + wn + fj * 16 + r;
      const float bn_ = bias[n];
#pragma unroll
      for (int rr = 0; rr < 4; ++rr) {
        const int m = bm + wm + fi * 16 + kg * 4 + rr;
        const float v = acc[fi][fj][rr] + bn_;
        if (BF16_OUT) ((ushort*)Cv)[(size_t)m * N + n] = f2bf(v);
        else          ((float*)Cv)[(size_t)m * N + n] = v;
      }
    }
}

// ---------------- MFMA attention (unchanged) ----------------
__global__ __launch_bounds__(256) void attn_mfma_k(
    const ushort* __restrict__ qkv, ushort* __restrict__ xout) {
  extern __shared__ ushort smem[];
  ushort* Klds = smem;
  ushort* Vlds = smem + 16384;
  const int bh = blockIdx.x;
  const int b = bh >> 2, h = bh & 3;
  const int tid = threadIdx.x;
  const int lane = tid & 63, w = tid >> 6;
  const int r = lane & 15, kg = lane >> 4;
  const ushort* qb = qkv + (size_t)(b * Lc) * 768 + h * 64;
  const ushort* kb = qb + 256;
  const ushort* vb = qb + 512;
#pragma unroll
  for (int i = 0; i < 8; ++i) {
    const int c = i * 256 + tid;
    const int key = c >> 3, kc = c & 7;
    short8 v = *(const short8*)(kb + (size_t)key * 768 + kc * 8);
    *(short8*)((char*)Klds + key * 128 + ((kc * 16) ^ ((key & 7) << 4))) = v;
  }
#pragma unroll
  for (int i = 0; i < 8; ++i) {
    const int c = i * 256 + tid;
    const int key = c >> 3, dc = c & 7;
    short8 v = *(const short8*)(vb + (size_t)key * 768 + dc * 8);
#pragma unroll
    for (int j = 0; j < 8; ++j) {
      const int d = dc * 8 + j;
      *(ushort*)((char*)Vlds + d * 512 + ((key * 2) ^ ((d & 7) << 4))) = (ushort)v[j];
    }
  }
  __syncthreads();

#pragma unroll 1
  for (int it = 0; it < 4; ++it) {
    const int qbase = it * 64 + w * 16;
    short8 bq0 = *(const short8*)(qb + (size_t)(qbase + r) * 768 + kg * 8);
    short8 bq1 = *(const short8*)(qb + (size_t)(qbase + r) * 768 + 32 + kg * 8);
    f32x4 accs[16];
#pragma unroll
    for (int fi = 0; fi < 16; ++fi) accs[fi] = (f32x4){0.f, 0.f, 0.f, 0.f};
#pragma unroll
    for (int fi = 0; fi < 16; ++fi) {
      const int key = fi * 16 + r;
      short8 ak0 = *(const short8*)((const char*)Klds + key * 128 + ((kg * 16) ^ ((key & 7) << 4)));
      short8 ak1 = *(const short8*)((const char*)Klds + key * 128 + ((64 + kg * 16) ^ ((key & 7) << 4)));
      accs[fi] = __builtin_amdgcn_mfma_f32_16x16x32_bf16(ak0, bq0, accs[fi], 0, 0, 0);
      accs[fi] = __builtin_amdgcn_mfma_f32_16x16x32_bf16(ak1, bq1, accs[fi], 0, 0, 0);
    }
    float m = -1e30f;
#pragma unroll
    for (int fi = 0; fi < 16; ++fi)
#pragma unroll
      for (int rr = 0; rr < 4; ++rr) m = fmaxf(m, accs[fi][rr]);
    m = fmaxf(m, __shfl_xor(m, 16));
    m = fmaxf(m, __shfl_xor(m, 32));
    float den = 0.f;
#pragma unroll
    for (int fi = 0; fi < 16; ++fi)
#pragma unroll
      for (int rr = 0; rr < 4; ++rr) {
        const float e = __expf((accs[fi][rr] - m) * 0.125f);
        accs[fi][rr] = e;
        den += e;
      }
    den += __shfl_xor(den, 16);
    den += __shfl_xor(den, 32);
    const float rp = vrcp(den);
    unsigned u[16][2];
#pragma unroll
    for (int fi = 0; fi < 16; ++fi) {
      u[fi][0] = cvtpk(accs[fi][0] * rp, accs[fi][1] * rp);
      u[fi][1] = cvtpk(accs[fi][2] * rp, accs[fi][3] * rp);
    }
    short8 bpv[8];
#pragma unroll
    for (int ks2 = 0; ks2 < 8; ++ks2) {
      uint4v vals;
#pragma unroll
      for (int m2 = 0; m2 < 4; ++m2) {
        const int src = r + (((kg & 1) * 2 + (m2 >> 1)) << 4);
        const unsigned lo = __shfl(u[2 * ks2][m2 & 1], src);
        const unsigned hi = __shfl(u[2 * ks2 + 1][m2 & 1], src);
        vals[m2] = (kg >= 2) ? hi : lo;
      }
      union { uint4v u4; short8 s8; } cv;
      cv.u4 = vals;
      bpv[ks2] = cv.s8;
    }
    f32x4 acco[4];
#pragma unroll
    for (int fj = 0; fj < 4; ++fj) acco[fj] = (f32x4){0.f, 0.f, 0.f, 0.f};
#pragma unroll
    for (int fj = 0; fj < 4; ++fj) {
      const int d = fj * 16 + r;
#pragma unroll
      for (int ks2 = 0; ks2 < 8; ++ks2) {
        short8 bv = *(const short8*)((const char*)Vlds + d * 512 +
                                     ((ks2 * 64 + kg * 16) ^ ((d & 7) << 4)));
        acco[fj] = __builtin_amdgcn_mfma_f32_16x16x32_bf16(bpv[ks2], bv, acco[fj], 0, 0, 0);
      }
    }
#pragma unroll
    for (int fj = 0; fj < 4; ++fj)
#pragma unroll
      for (int rr = 0; rr < 4; ++rr) {
        const int q = qbase + kg * 4 + rr;
        xout[((size_t)(b * Lc + q)) * 256 + h * 64 + fj * 16 + r] = f2bf(acco[fj][rr]);
      }
  }
}

// ---------------- transpose gx -> gxt [s][dir][grow][b][r], fold bhh, scale by -log2e ----------------
__global__ __launch_bounds__(256) void transpose_gx_k(
    const ushort* __restrict__ gx, const float* __restrict__ bhhf,
    const float* __restrict__ bhhb, ushort* __restrict__ gxt) {
  const int s = blockIdx.x, dir = blockIdx.y;
  const int t = threadIdx.x;
  const int b = t & 63;
  const int c = t >> 6;
  const float* bhh = dir ? bhhb : bhhf;
  const size_t obase = (size_t)(s * 2 + dir) * 32768;
#pragma unroll 4
  for (int i = 0; i < 16; ++i) {
    const int g8 = i * 4 + c;
    short8 v = *(const short8*)(gx + ((size_t)b * 256 + s) * 1024 + dir * 512 + g8 * 8);
    float f[8];
#pragma unroll
    for (int j = 0; j < 8; ++j) f[j] = (bf2f((ushort)v[j]) + bhh[g8 * 8 + j]) * NL2E;
    uint2 lo = make_uint2(cvtpk(f[0], f[1]), cvtpk(f[2], f[3]));
    uint2 hi = make_uint2(cvtpk(f[4], f[5]), cvtpk(f[6], f[7]));
    *(uint2*)(gxt + obase + (size_t)(g8 * 2) * 256 + b * 4) = lo;
    *(uint2*)(gxt + obase + (size_t)(g8 * 2 + 1) * 256 + b * 4) = hi;
  }
}

// ---------------- MFMA BiLSTM (R12 version: 8 blocks, 512 thr; exp2 activations) ----------------
__global__ __launch_bounds__(512, 2) void lstm_mfma_k(
    const ushort* __restrict__ gxt, const ushort* __restrict__ whh,
    const float* __restrict__ h0, const float* __restrict__ c0,
    ushort* __restrict__ louts) {
  const int bs = blockIdx.x * 16;
  const int dir = blockIdx.y;
  const int tid = threadIdx.x;
  const int w = tid >> 6, lane = tid & 63;
  const int col = lane & 15;
  const int kg = lane >> 4;
  short8 afrag[4][4];
#pragma unroll
  for (int g = 0; g < 4; ++g)
#pragma unroll
    for (int ks = 0; ks < 4; ++ks)
      afrag[g][ks] = *(const short8*)(whh + (size_t)dir * 65536 +
                                      (size_t)(g * 128 + w * 16 + col) * 128 + ks * 32 + kg * 8);
  float4 c4 = *(const float4*)(c0 + (size_t)(dir * Bc + bs + col) * 128 + w * 16 + kg * 4);
  __shared__ __align__(16) ushort hlds[2][2048];
  {
    float4 h4 = *(const float4*)(h0 + (size_t)(dir * Bc + bs + col) * 128 + w * 16 + kg * 4);
    const int wb = (col * 256 + w * 32 + kg * 8) ^ ((col & 7) << 4);
    *(uint2*)((char*)hlds[0] + wb) = make_uint2(cvtpk(h4.x, h4.y), cvtpk(h4.z, h4.w));
  }
  const ushort* gtb = gxt + (size_t)dir * 32768 + (size_t)(w * 4 + kg) * 256 + (size_t)(bs + col) * 4;
  const int step0 = dir ? (Lc - 1) : 0;
  const int dstep = dir ? -1 : 1;
  const ptrdiff_t gstride = (ptrdiff_t)dstep * 65536;
  const ptrdiff_t lstride = (ptrdiff_t)dstep * 16384;
  ushort4v gA[4], gB[4];
#pragma unroll
  for (int g = 0; g < 4; ++g) gA[g] = *(const ushort4v*)(gtb + (size_t)step0 * 65536 + g * 8192);
#pragma unroll
  for (int g = 0; g < 4; ++g) gB[g] = *(const ushort4v*)(gtb + (size_t)(step0 + dstep) * 65536 + g * 8192);
  const ushort* gld = gtb + (size_t)step0 * 65536 + 2 * gstride;
  ushort* lst = louts + (size_t)step0 * 16384 + dir * 8192 + w * 1024 + kg * 256 +
                (size_t)(bs + col) * 4;
  __syncthreads();
  int p = 0;

  auto body = [&](ushort4v (&gcur)[4], bool pfok) {
    short8 bfrag[4];
#pragma unroll
    for (int ks = 0; ks < 4; ++ks) {
      const int rb = (col * 256 + ks * 64 + kg * 16) ^ ((col & 7) << 4);
      bfrag[ks] = *(const short8*)((const char*)hlds[p] + rb);
    }
    f32x4 acc[4];
#pragma unroll
    for (int g = 0; g < 4; ++g)
      acc[g] = (f32x4){bf2f(gcur[g][0]), bf2f(gcur[g][1]), bf2f(gcur[g][2]), bf2f(gcur[g][3])};
    if (pfok) {
#pragma unroll
      for (int g = 0; g < 4; ++g) gcur[g] = *(const ushort4v*)(gld + g * 8192);
      gld += gstride;
    }
#pragma unroll
    for (int ks = 0; ks < 4; ++ks)
#pragma unroll
      for (int g = 0; g < 4; ++g)
        acc[g] = __builtin_amdgcn_mfma_f32_16x16x32_bf16(afrag[g][ks], bfrag[ks], acc[g], 0, 0, 0);
    f32x4 hr;
#pragma unroll
    for (int r = 0; r < 4; ++r) {
      const float ii = vrcp(1.f + vexp2(acc[0][r]));
      const float ff = vrcp(1.f + vexp2(acc[1][r]));
      const float gg = fmaf(-2.f, vrcp(1.f + vexp2(acc[2][r] * -2.f)), 1.f);
      const float oo = vrcp(1.f + vexp2(acc[3][r]));
      const float cn = ff * c4[r] + ii * gg;
      c4[r] = cn;
      const float tc = fmaf(-2.f, vrcp(1.f + vexp2(cn * 2.8853900817779268f)), 1.f);
      hr[r] = oo * tc;
    }
    const uint2 hp2 = make_uint2(cvtpk(hr[0], hr[1]), cvtpk(hr[2], hr[3]));
    const int wb = (col * 256 + w * 32 + kg * 8) ^ ((col & 7) << 4);
    *(uint2*)((char*)hlds[p ^ 1] + wb) = hp2;
    *(uint2*)lst = hp2;
    lst += lstride;
    asm volatile("s_waitcnt lgkmcnt(0)" ::: "memory");
    __builtin_amdgcn_s_barrier();
    asm volatile("" ::: "memory");
    p ^= 1;
  };

  for (int s = 0; s < Lc; s += 2) {
    body(gA, s + 2 < Lc);
    body(gB, s + 3 < Lc);
  }
}

// ---------------- logits (unchanged) ----------------
__global__ __launch_bounds__(256) void logits_k(
    const ushort* __restrict__ louts, const float* __restrict__ woutp,
    const float* __restrict__ bout, float* __restrict__ lg) {
  const int s = blockIdx.x;
  const int t = threadIdx.x;
  __shared__ float wls[20 * 256];
  __shared__ float bls[20];
  for (int i = t; i < 20 * 256; i += 256) wls[i] = woutp[i];
  if (t < 20) bls[t] = bout[t];
  __syncthreads();
  const int b = t & 63, tg = t >> 6;
  const ushort* src = louts + (size_t)s * 16384 + b * 4;
  float acc[5] = {0.f, 0.f, 0.f, 0.f, 0.f};
  for (int pc = 0; pc < 64; ++pc) {
    ushort4v x4 = *(const ushort4v*)(src + pc * 256);
    const float x0 = bf2f(x4[0]), x1 = bf2f(x4[1]), x2 = bf2f(x4[2]), x3 = bf2f(x4[3]);
#pragma unroll
    for (int n = 0; n < 5; ++n) {
      const float* w4 = wls + (tg * 5 + n) * 256 + pc * 4;
      acc[n] += x0 * w4[0] + x1 * w4[1] + x2 * w4[2] + x3 * w4[3];
    }
  }
#pragma unroll
  for (int n = 0; n < 5; ++n)
    lg[((size_t)b * Lc + s) * NTc + tg * 5 + n] = acc[n] + bls[tg * 5 + n];
}

// ---------------- CRF: single-wave shfl scan in log2 space (unchanged) ----------------
__global__ __launch_bounds__(64) void crf_fwd_k(
    const float* __restrict__ lg, const int* __restrict__ tags,
    const int* __restrict__ lens, const float* __restrict__ tr,
    float* __restrict__ part) {
  const int b = blockIdx.x, j = threadIdx.x;
  const float L2E = 1.4426950408889634f;
  __shared__ float tl[NTc * NTc];
  for (int i = j; i < NTc * NTc; i += 64) tl[i] = tr[i];
  __syncthreads();
  const int len = lens[b];
  float gv = 0.f;
  for (int t = j; t < len; t += 64) {
    const int tag = tags[b * Lc + t];
    const int pv = (t == 0) ? START_c : tags[b * Lc + t - 1];
    gv += lg[((size_t)b * Lc + t) * NTc + tag] + tl[pv * NTc + tag];
  }
#pragma unroll
  for (int off = 32; off > 0; off >>= 1) gv += __shfl_xor(gv, off);
  const int jj = (j < NTc) ? j : 0;
  float trc2[NTc];
#pragma unroll
  for (int i = 0; i < NTc; ++i) trc2[i] = tl[i * NTc + jj] * L2E;
  float prev2 = 0.f;
  float lgn = lg[(size_t)b * Lc * NTc + jj];
  for (int t = 0; t < len; ++t) {
    const float lg2 = lgn * L2E;
    if (t + 1 < len) lgn = lg[((size_t)b * Lc + t + 1) * NTc + jj];
    float v[NTc];
#pragma unroll
    for (int i = 0; i < NTc; ++i) v[i] = __shfl(prev2, i) + trc2[i];
    float a0 = fmaxf(v[0], v[1]), a1 = fmaxf(v[2], v[3]), a2 = fmaxf(v[4], v[5]);
    float a3 = fmaxf(v[6], v[7]), a4 = fmaxf(v[8], v[9]), a5 = fmaxf(v[10], v[11]);
    float a6 = fmaxf(v[12], v[13]), a7 = fmaxf(v[14], v[15]), a8 = fmaxf(v[16], v[17]);
    float a9 = fmaxf(v[18], v[19]);
    float b0 = fmaxf(fmaxf(a0, a1), a2), b1 = fmaxf(fmaxf(a3, a4), a5);
    float b2 = fmaxf(fmaxf(a6, a7), a8);
    const float m = fmaxf(fmaxf(b0, b1), fmaxf(b2, a9));
    float s0 = 0.f, s1 = 0.f, s2 = 0.f, s3 = 0.f;
#pragma unroll
    for (int i = 0; i < NTc; i += 4) {
      s0 += vexp2(v[i] - m);
      s1 += vexp2(v[i + 1] - m);
      s2 += vexp2(v[i + 2] - m);
      s3 += vexp2(v[i + 3] - m);
    }
    prev2 = m + vlog2((s0 + s1) + (s2 + s3)) + lg2;
  }
  float fv[NTc];
#pragma unroll
  for (int i = 0; i < NTc; ++i) fv[i] = __shfl(prev2, i) + tl[i * NTc + STOP_c] * L2E;
  float a0 = fmaxf(fv[0], fv[1]), a1 = fmaxf(fv[2], fv[3]), a2 = fmaxf(fv[4], fv[5]);
  float a3 = fmaxf(fv[6], fv[7]), a4 = fmaxf(fv[8], fv[9]), a5 = fmaxf(fv[10], fv[11]);
  float a6 = fmaxf(fv[12], fv[13]), a7 = fmaxf(fv[14], fv[15]), a8 = fmaxf(fv[16], fv[17]);
  float a9 = fmaxf(fv[18], fv[19]);
  float b0 = fmaxf(fmaxf(a0, a1), a2), b1 = fmaxf(fmaxf(a3, a4), a5);
  float b2 = fmaxf(fmaxf(a6, a7), a8);
  const float m = fmaxf(fmaxf(b0, b1), fmaxf(b2, a9));
  float ssum = 0.f;
#pragma unroll
  for (int i = 0; i < NTc; ++i) ssum += vexp2(fv[i] - m);
  if (j == 0) {
    const int lt = tags[b * Lc + len - 1];
    const float realv = gv + tl[lt * NTc + STOP_c];
    const float total = (m + vlog2(ssum)) * 0.6931471805599453f;
    part[b] = total - realv;
  }
}

__global__ __launch_bounds__(64) void final_sum_k(const float* __restrict__ part, float* __restrict__ out) {
  float v = part[threadIdx.x];
#pragma unroll
  for (int off = 32; off > 0; off >>= 1) v += __shfl_down(v, off);
  if (threadIdx.x == 0) out[0] = v;
}

extern "C" void kernel_launch(void* const* d_in, const int* in_sizes, int n_in,
                              void* d_out, int out_size, void* d_ws, size_t ws_size,
                              hipStream_t stream) {
  const int* sent = (const int*)d_in[0];
  const int* bush = (const int*)d_in[1];
  const float* pin = (const float*)d_in[2];
  const float* wz = (const float*)d_in[3];
  const float* twz = (const float*)d_in[4];
  const int* tags = (const int*)d_in[5];
  const int* lens = (const int*)d_in[6];
  const float* emb1 = (const float*)d_in[7];
  const float* emb2 = (const float*)d_in[8];
  const float* Wq = (const float*)d_in[9];  const float* bq = (const float*)d_in[10];
  const float* Wk = (const float*)d_in[11]; const float* bk = (const float*)d_in[12];
  const float* Wv = (const float*)d_in[13]; const float* bv = (const float*)d_in[14];
  const float* Wo = (const float*)d_in[15]; const float* bo = (const float*)d_in[16];
  const float* Wihf = (const float*)d_in[17]; const float* Whhf = (const float*)d_in[18];
  const float* bihf = (const float*)d_in[19]; const float* bhhf = (const float*)d_in[20];
  const float* Wihb = (const float*)d_in[21]; const float* Whhb = (const float*)d_in[22];
  const float* bihb = (const float*)d_in[23]; const float* bhhb = (const float*)d_in[24];
  const float* Wout = (const float*)d_in[25]; const float* bout = (const float*)d_in[26];
  const float* trans = (const float*)d_in[27];
  const float* h0 = (const float*)d_in[28]; const float* c0 = (const float*)d_in[29];
  float* out = (float*)d_out;
  float* w = (float*)d_ws;
  ushort* finb  = (ushort*)w;
  ushort* axb   = (ushort*)w;
  ushort* qkvb  = (ushort*)(w + 2097152);
  ushort* gxb   = (ushort*)(w + 8388608);
  ushort* gxt   = (ushort*)w;
  ushort* louts = (ushort*)(w + 8388608);
  float*  lgts  = w + 10485760;
  size_t off = 16777216;
  ushort* wqkvb  = (ushort*)(w + off); off += 768 * 256 / 2;
  ushort* wihbf  = (ushort*)(w + off); off += 1024 * 256 / 2;
  ushort* woTb   = (ushort*)(w + off); off += 256 * 256 / 2;
  ushort* wcombb = (ushort*)(w + off); off += 1024 * 256 / 2;
  ushort* whhp   = (ushort*)(w + off); off += 2 * 512 * 128 / 2;
  float* woutp = w + off; off += 20 * 256;
  float* bqkv  = w + off; off += 768;
  float* bcomb = w + off; off += 1024;
  float* zbias = w + off; off += 256;
  float* partv = w + off;

  prep_fin_k<<<16384 + 569, 256, 0, stream>>>(
      sent, bush, pin, wz, twz, emb1, emb2, finb,
      Wq, Wk, Wv, Wo, Wihf, Wihb, Whhf, Whhb, Wout,
      bq, bk, bv, bo, bihf, bihb,
      wqkvb, wihbf, whhp, woutp, woTb, bqkv, bcomb, zbias);
  // Wcomb[j][k] = sum_n Wih[j][n] * Wo[n][k]
  mfma_gemm_k<256, true><<<dim3(8, 2), 256, 0, stream>>>(wihbf, woTb, zbias, wcombb);
  mfma_gemm_k<768, true><<<dim3(128, 6), 256, 0, stream>>>(finb, wqkvb, bqkv, qkvb);
  attn_mfma_k<<<Bc * 4, 256, 65536, stream>>>(qkvb, axb);
  // gx = attn_out @ Wcomb^T + bcomb   (O-proj fused in)
  mfma_gemm_k<1024, true><<<dim3(128, 8), 256, 0, stream>>>(axb, wcombb, bcomb, gxb);
  transpose_gx_k<<<dim3(256, 2), 256, 0, stream>>>(gxb, bhhf, bhhb, gxt);
  lstm_mfma_k<<<dim3(4, 2), 512, 0, stream>>>(gxt, whhp, h0, c0, louts);
  logits_k<<<Lc, 256, 0, stream>>>(louts, woutp, bout, lgts);
  crf_fwd_k<<<Bc, 64, 0, stream>>>(lgts, tags, lens, trans, partv);
  final_sum_k<<<1, 64, 0, stream>>>(partv, out);
}